// Round 8
// baseline (402.933 us; speedup 1.0000x reference)
//
#include <hip/hip_runtime.h>

#define N_NODES 100000
#define SCAN_NB 128
#define SCAN_TPB 256

typedef _Float16 half_t;
typedef __attribute__((ext_vector_type(8))) _Float16 v8h;
typedef __attribute__((ext_vector_type(4))) _Float16 v4h;
typedef __attribute__((ext_vector_type(4))) float v4f;

// ---------------- prep1: degree count + weight transpose/convert ----------------

__global__ void prep1(const int* __restrict__ src, const int* __restrict__ dst,
                      int* __restrict__ ocnt, int* __restrict__ icnt, int E,
                      const float* __restrict__ W1, const float* __restrict__ W2,
                      const float* __restrict__ W3, half_t* __restrict__ Wt1,
                      half_t* __restrict__ Wt2, half_t* __restrict__ Wt3) {
    int t = blockIdx.x * blockDim.x + threadIdx.x;
    if (t < E) {
        atomicAdd(&ocnt[src[t]], 1);
        atomicAdd(&icnt[dst[t]], 1);
    } else {
        int u = t - E;
        if (u < 32768) {                      // W1: K=128, N=256
            int n = u >> 7, k = u & 127;
            Wt1[u] = (half_t)W1[(size_t)k * 256 + n];
        } else if (u < 65536) {               // W2: K=256, N=128
            int w = u - 32768;
            int n = w >> 8, k = w & 255;
            Wt2[w] = (half_t)W2[(size_t)k * 128 + n];
        } else if (u < 70656) {               // W3: K=128, N=40
            int w = u - 65536;
            int n = w >> 7, k = w & 127;
            Wt3[w] = (half_t)W3[(size_t)k * 40 + n];
        }
    }
}

// ---------------- scan (3-phase hierarchical) ----------------

__global__ __launch_bounds__(SCAN_TPB) void scan_reduce(const int* __restrict__ cnt,
                                                        int* __restrict__ blockSum, int n) {
    __shared__ int s[SCAN_TPB];
    int chunk = (n + SCAN_NB - 1) / SCAN_NB;
    int beg = blockIdx.x * chunk;
    int end = min(beg + chunk, n);
    int sum = 0;
    for (int i = beg + threadIdx.x; i < end; i += SCAN_TPB) sum += cnt[i];
    s[threadIdx.x] = sum;
    __syncthreads();
    for (int off = SCAN_TPB / 2; off > 0; off >>= 1) {
        if (threadIdx.x < off) s[threadIdx.x] += s[threadIdx.x + off];
        __syncthreads();
    }
    if (threadIdx.x == 0) blockSum[blockIdx.x] = s[0];
}

__global__ __launch_bounds__(SCAN_NB) void scan_offsets(int* __restrict__ blockSum,
                                                        int* __restrict__ rowptr_total) {
    __shared__ int s[SCAN_NB];
    int tid = threadIdx.x;
    int v = blockSum[tid];
    s[tid] = v;
    __syncthreads();
    for (int off = 1; off < SCAN_NB; off <<= 1) {
        int t = (tid >= off) ? s[tid - off] : 0;
        __syncthreads();
        s[tid] += t;
        __syncthreads();
    }
    blockSum[tid] = s[tid] - v;
    if (tid == SCAN_NB - 1) rowptr_total[0] = s[tid];
}

// Phase 3: in-chunk scan + block offset -> rowptr, cursor; also converts
// ocnt/icnt (int degree) -> inv-sqrt norms (float, in place).
__global__ __launch_bounds__(SCAN_TPB) void scan_final(int* __restrict__ cnt,
                                                       int* __restrict__ ocnt,
                                                       const int* __restrict__ blockSum,
                                                       int* __restrict__ rowptr,
                                                       int* __restrict__ cursor, int n) {
    __shared__ int s[SCAN_TPB];
    int chunk = (n + SCAN_NB - 1) / SCAN_NB;
    int beg = blockIdx.x * chunk;
    int end = min(beg + chunk, n);
    int carry = blockSum[blockIdx.x];
    for (int base = beg; base < end; base += SCAN_TPB) {
        int i = base + threadIdx.x;
        int v = (i < end) ? cnt[i] : 0;
        s[threadIdx.x] = v;
        __syncthreads();
        for (int off = 1; off < SCAN_TPB; off <<= 1) {
            int t = (threadIdx.x >= off) ? s[threadIdx.x - off] : 0;
            __syncthreads();
            s[threadIdx.x] += t;
            __syncthreads();
        }
        int excl = s[threadIdx.x] - v;
        if (i < end) {
            rowptr[i] = carry + excl;
            cursor[i] = carry + excl;
            int o = ocnt[i];
            ((float*)ocnt)[i] = rsqrtf((float)max(o, 1));
            ((float*)cnt)[i] = rsqrtf((float)max(v, 1));
        }
        int roundSum = s[SCAN_TPB - 1];
        __syncthreads();
        carry += roundSum;
    }
}

// ---------------- prep2: CSR fill + x convert (x * inv_out -> fp16) ----------------

__global__ void prep2(const int* __restrict__ src, const int* __restrict__ dst,
                      int* __restrict__ cursor, int* __restrict__ eidx, int E,
                      const float* __restrict__ x, const float* __restrict__ invOut,
                      half_t* __restrict__ xh) {
    int t = blockIdx.x * blockDim.x + threadIdx.x;
    if (t < E) {
        int pos = atomicAdd(&cursor[dst[t]], 1);
        eidx[pos] = src[t];
    } else {
        int u = t - E;
        if (u < N_NODES * 32) {
            int n = u >> 5;
            float4 v = ((const float4*)x)[u];
            float s = invOut[n];
            v4h h;
            h[0] = (half_t)(v.x * s);
            h[1] = (half_t)(v.y * s);
            h[2] = (half_t)(v.z * s);
            h[3] = (half_t)(v.w * s);
            *(v4h*)(xh + (size_t)u * 4) = h;
        }
    }
}

// ---------------- 8/4/1-unrolled CSR row segment-sum into fp32 acc[8] ----------------

template <int F>
__device__ __forceinline__ void gather_row(const half_t* __restrict__ x,
                                           const int* __restrict__ eidx,
                                           int beg, int end, int c, float* acc) {
    int j = beg;
    int len = end - beg;
    int n8 = beg + (len & ~7);
    for (; j < n8; j += 8) {
        int s0 = eidx[j + 0], s1 = eidx[j + 1], s2 = eidx[j + 2], s3 = eidx[j + 3];
        int s4 = eidx[j + 4], s5 = eidx[j + 5], s6 = eidx[j + 6], s7 = eidx[j + 7];
        v8h v0 = *(const v8h*)(x + (size_t)s0 * F + c * 8);
        v8h v1 = *(const v8h*)(x + (size_t)s1 * F + c * 8);
        v8h v2 = *(const v8h*)(x + (size_t)s2 * F + c * 8);
        v8h v3 = *(const v8h*)(x + (size_t)s3 * F + c * 8);
        v8h v4 = *(const v8h*)(x + (size_t)s4 * F + c * 8);
        v8h v5 = *(const v8h*)(x + (size_t)s5 * F + c * 8);
        v8h v6 = *(const v8h*)(x + (size_t)s6 * F + c * 8);
        v8h v7 = *(const v8h*)(x + (size_t)s7 * F + c * 8);
#pragma unroll
        for (int q = 0; q < 8; ++q)
            acc[q] += (((float)v0[q] + (float)v1[q]) + ((float)v2[q] + (float)v3[q])) +
                      (((float)v4[q] + (float)v5[q]) + ((float)v6[q] + (float)v7[q]));
    }
    if ((end - j) >= 4) {
        int s0 = eidx[j + 0], s1 = eidx[j + 1], s2 = eidx[j + 2], s3 = eidx[j + 3];
        v8h v0 = *(const v8h*)(x + (size_t)s0 * F + c * 8);
        v8h v1 = *(const v8h*)(x + (size_t)s1 * F + c * 8);
        v8h v2 = *(const v8h*)(x + (size_t)s2 * F + c * 8);
        v8h v3 = *(const v8h*)(x + (size_t)s3 * F + c * 8);
#pragma unroll
        for (int q = 0; q < 8; ++q)
            acc[q] += ((float)v0[q] + (float)v1[q]) + ((float)v2[q] + (float)v3[q]);
        j += 4;
    }
    for (; j < end; ++j) {
        int s = eidx[j];
        v8h val = *(const v8h*)(x + (size_t)s * F + c * 8);
#pragma unroll
        for (int q = 0; q < 8; ++q) acc[q] += (float)val[q];
    }
}

// ---------------- fused gather + GEMM1 + GEMM2 (layers 1+2 transform) ----------
// A-tile (64 rows) = segsum(xh) via CSR gather; h1 = relu((A@W1)*invIn+b1)*invOut
// kept in LDS only; t2 = h1 @ W2 -> global fp16. B1/B2 fragments in registers.

__global__ __launch_bounds__(256) void fused_l12(
    const half_t* __restrict__ xh, const int* __restrict__ rowptr,
    const int* __restrict__ eidx, const half_t* __restrict__ Wt1,
    const half_t* __restrict__ Wt2,
    const float* __restrict__ invIn, const float* __restrict__ invOut,
    const float* __restrict__ b1, half_t* __restrict__ t2) {
    constexpr int K1 = 128, K2 = 256, N2 = 128;
    constexpr int LDA = K1 + 8;
    constexpr int LDH = K2 + 8;
    __shared__ half_t As[64][LDA];
    __shared__ half_t h1S[64][LDH];
    __shared__ float iiS[64], ioS[64];
    const int tid = threadIdx.x;
    const int wave = tid >> 6, lane = tid & 63;
    const int quad = lane >> 4, l16 = lane & 15;
    const int m0 = blockIdx.x * 64;
    const int n0 = wave * 64;

    v8h b[4][4];
    float bv[4];
#pragma unroll
    for (int j = 0; j < 4; ++j) {
        int gn = n0 + j * 16 + l16;
        bv[j] = b1[gn];
#pragma unroll
        for (int kc = 0; kc < 4; ++kc)
            b[j][kc] = *(const v8h*)(Wt1 + (size_t)gn * K1 + kc * 32 + quad * 8);
    }
    if (tid < 64) {
        int gm = m0 + tid;
        bool ok = gm < N_NODES;
        iiS[tid] = ok ? invIn[gm] : 0.f;
        ioS[tid] = ok ? invOut[gm] : 0.f;
    }

    // gather phase: 64 rows x 16 chunks = 1024 tasks, 4 per thread
#pragma unroll
    for (int t = 0; t < 4; ++t) {
        int task = tid + t * 256;
        int r = task >> 4, c = task & 15;
        int gm = m0 + r;
        float acc[8] = {};
        if (gm < N_NODES)
            gather_row<K1>(xh, eidx, rowptr[gm], rowptr[gm + 1], c, acc);
        v8h o;
#pragma unroll
        for (int q = 0; q < 8; ++q) o[q] = (half_t)acc[q];
        *(v8h*)&As[r][c * 8] = o;
    }
    __syncthreads();

    // GEMM1 -> h1S (LDS)
    for (int mt = 0; mt < 4; ++mt) {
        v8h a[4];
#pragma unroll
        for (int kc = 0; kc < 4; ++kc)
            a[kc] = *(const v8h*)&As[mt * 16 + l16][kc * 32 + quad * 8];
        v4f acc[4] = {};
#pragma unroll
        for (int kc = 0; kc < 4; ++kc)
#pragma unroll
            for (int j = 0; j < 4; ++j)
                acc[j] = __builtin_amdgcn_mfma_f32_16x16x32_f16(a[kc], b[j][kc], acc[j], 0, 0, 0);
#pragma unroll
        for (int j = 0; j < 4; ++j) {
            int cn = n0 + j * 16 + l16;
#pragma unroll
            for (int r = 0; r < 4; ++r) {
                int lr = mt * 16 + quad * 4 + r;
                float z = (acc[j][r] * iiS[lr] + bv[j]) * ioS[lr];
                h1S[lr][cn] = (half_t)fmaxf(z, 0.f);
            }
        }
    }

    // B2 fragments
    v8h b2[2][8];
    const int n02 = wave * 32;
#pragma unroll
    for (int j = 0; j < 2; ++j) {
        int gn = n02 + j * 16 + l16;
#pragma unroll
        for (int kc = 0; kc < 8; ++kc)
            b2[j][kc] = *(const v8h*)(Wt2 + (size_t)gn * K2 + kc * 32 + quad * 8);
    }
    __syncthreads();

    // GEMM2: t2 = h1S @ W2
    for (int mt = 0; mt < 4; ++mt) {
        v8h a2[8];
#pragma unroll
        for (int kc = 0; kc < 8; ++kc)
            a2[kc] = *(const v8h*)&h1S[mt * 16 + l16][kc * 32 + quad * 8];
        v4f acc2[2] = {};
#pragma unroll
        for (int kc = 0; kc < 8; ++kc)
#pragma unroll
            for (int j = 0; j < 2; ++j)
                acc2[j] = __builtin_amdgcn_mfma_f32_16x16x32_f16(a2[kc], b2[j][kc], acc2[j], 0, 0, 0);
#pragma unroll
        for (int j = 0; j < 2; ++j) {
            int gn = n02 + j * 16 + l16;
#pragma unroll
            for (int r = 0; r < 4; ++r) {
                int gm = m0 + mt * 16 + quad * 4 + r;
                if (gm < N_NODES)
                    __builtin_nontemporal_store((half_t)acc2[j][r], &t2[(size_t)gm * N2 + gn]);
            }
        }
    }
}

// ---------------- fused gather(+relu epi) + GEMM, layer 3 ----------------

__global__ __launch_bounds__(256) void fused_l3(
    const half_t* __restrict__ t2, const int* __restrict__ rowptr,
    const int* __restrict__ eidx, const half_t* __restrict__ Wt3,
    const float* __restrict__ invIn, const float* __restrict__ invOut,
    const float* __restrict__ b2, half_t* __restrict__ t3) {
    constexpr int K = 128, N = 40, LDA = K + 8;
    __shared__ half_t As[64][LDA];
    const int tid = threadIdx.x;
    const int wave = tid >> 6, lane = tid & 63;
    const int quad = lane >> 4, l16 = lane & 15;
    const int m0 = blockIdx.x * 64;

    v8h b[3][4];
#pragma unroll
    for (int j = 0; j < 3; ++j) {
        int gn = j * 16 + l16;
#pragma unroll
        for (int kc = 0; kc < 4; ++kc)
            b[j][kc] = (gn < N) ? *(const v8h*)(Wt3 + (size_t)gn * K + kc * 32 + quad * 8)
                                : (v8h)(half_t)0;
    }

#pragma unroll
    for (int t = 0; t < 4; ++t) {
        int task = tid + t * 256;
        int r = task >> 4, c = task & 15;
        int gm = m0 + r;
        float acc[8] = {};
        float ii = 0.f, io = 0.f;
        if (gm < N_NODES) {
            ii = invIn[gm];
            io = invOut[gm];
            gather_row<K>(t2, eidx, rowptr[gm], rowptr[gm + 1], c, acc);
        }
        v8h o;
#pragma unroll
        for (int q = 0; q < 8; ++q)
            o[q] = (half_t)fmaxf((acc[q] * ii + b2[c * 8 + q]) * io, 0.f);
        *(v8h*)&As[r][c * 8] = o;
    }
    __syncthreads();

    {
        int mt = wave;
        v8h a[4];
#pragma unroll
        for (int kc = 0; kc < 4; ++kc)
            a[kc] = *(const v8h*)&As[mt * 16 + l16][kc * 32 + quad * 8];
        v4f acc[3] = {};
#pragma unroll
        for (int kc = 0; kc < 4; ++kc)
#pragma unroll
            for (int j = 0; j < 3; ++j)
                acc[j] = __builtin_amdgcn_mfma_f32_16x16x32_f16(a[kc], b[j][kc], acc[j], 0, 0, 0);
#pragma unroll
        for (int j = 0; j < 3; ++j) {
            int gn = j * 16 + l16;
            if (gn >= N) continue;
#pragma unroll
            for (int r = 0; r < 4; ++r) {
                int gm = m0 + mt * 16 + quad * 4 + r;
                if (gm < N_NODES)
                    __builtin_nontemporal_store((half_t)acc[j][r], &t3[(size_t)gm * N + gn]);
            }
        }
    }
}

// ---------------- final gather (fp16 rows, fp32 out) ----------------

__global__ void gather_final(const half_t* __restrict__ x,
                             const int* __restrict__ rowptr, const int* __restrict__ eidx,
                             float* __restrict__ out, const float* __restrict__ invIn,
                             const float* __restrict__ bias) {
    constexpr int F = 40, V = 5;
    int t = blockIdx.x * blockDim.x + threadIdx.x;
    int n = t / V;
    int v = t - n * V;
    if (n >= N_NODES) return;
    float acc[8] = {};
    gather_row<F>(x, eidx, rowptr[n], rowptr[n + 1], v, acc);
    float ii = invIn[n];
    float* o = out + (size_t)n * F + v * 8;
#pragma unroll
    for (int q = 0; q < 8; ++q)
        __builtin_nontemporal_store(acc[q] * ii + bias[v * 8 + q], &o[q]);
}

// ---------------- launch ----------------

extern "C" void kernel_launch(void* const* d_in, const int* in_sizes, int n_in,
                              void* d_out, int out_size, void* d_ws, size_t ws_size,
                              hipStream_t stream) {
    const float* x  = (const float*)d_in[0];
    const int* src  = (const int*)d_in[1];
    const int* dst  = (const int*)d_in[2];
    const float* W1 = (const float*)d_in[3];
    const float* b1 = (const float*)d_in[4];
    const float* W2 = (const float*)d_in[5];
    const float* b2 = (const float*)d_in[6];
    const float* W3 = (const float*)d_in[7];
    const float* b3 = (const float*)d_in[8];
    float* out = (float*)d_out;
    const int E = in_sizes[1];

    char* ws = (char*)d_ws;
    int* ocnt     = (int*)ws;                     // 100000 (becomes inv_out f32)
    int* icnt     = (int*)(ws + 400000);          // 100000 (becomes inv_in f32)
    int* rowptr   = (int*)(ws + 800000);          // 100001
    int* cursor   = (int*)(ws + 1200256);         // 100000
    int* eidx     = (int*)(ws + 1600256);         // 800000 (3.2 MB)
    int* blockSum = (int*)(ws + 4800256);         // 128
    half_t* Wt1   = (half_t*)(ws + 4800768);      // 256x128 fp16 (64 KB)
    half_t* Wt2   = (half_t*)(ws + 4866304);      // 128x256 fp16 (64 KB)
    half_t* Wt3   = (half_t*)(ws + 4931840);      // 40x128 fp16 (10 KB)
    half_t* buf0  = (half_t*)(ws + 5000192);      // 25.6 MB: xh, later t3
    half_t* buf1  = (half_t*)(ws + 30600192);     // 25.6 MB: t2
    const float* inv_out = (const float*)ocnt;
    const float* inv_in  = (const float*)icnt;

    // ---- CSR + norms + weight conversion ----
    hipMemsetAsync(ocnt, 0, 800000, stream);
    prep1<<<(E + 70656 + 255) / 256, 256, 0, stream>>>(src, dst, ocnt, icnt, E,
                                                       W1, W2, W3, Wt1, Wt2, Wt3);
    scan_reduce<<<SCAN_NB, SCAN_TPB, 0, stream>>>(icnt, blockSum, N_NODES);
    scan_offsets<<<1, SCAN_NB, 0, stream>>>(blockSum, rowptr + N_NODES);
    scan_final<<<SCAN_NB, SCAN_TPB, 0, stream>>>(icnt, ocnt, blockSum, rowptr, cursor, N_NODES);
    prep2<<<(E + N_NODES * 32 + 255) / 256, 256, 0, stream>>>(src, dst, cursor, eidx, E,
                                                              x, inv_out, buf0);

    const int NB = (N_NODES + 63) / 64;  // 1563

    // Layers 1+2: t2 = (relu((segsum(xh)@W1)*inv_in + b1)*inv_out) @ W2
    fused_l12<<<NB, 256, 0, stream>>>(buf0, rowptr, eidx, Wt1, Wt2,
                                      inv_in, inv_out, b1, buf1);
    // Layer 3: t3 = (relu((segsum(t2))*inv_in + b2)*inv_out) @ W3
    fused_l3<<<NB, 256, 0, stream>>>(buf1, rowptr, eidx, Wt3, inv_in, inv_out, b2, buf0);
    // Final gather: out = segsum(t3)*inv_in + b3
    gather_final<<<(N_NODES * 5 + 255) / 256, 256, 0, stream>>>(
        buf0, rowptr, eidx, out, inv_in, b3);
}

// Round 9
// 367.311 us; speedup vs baseline: 1.0970x; 1.0970x over previous
//
#include <hip/hip_runtime.h>

#define N_NODES 100000
#define SCAN_NB 128
#define SCAN_TPB 256

typedef _Float16 half_t;
typedef __attribute__((ext_vector_type(8))) _Float16 v8h;
typedef __attribute__((ext_vector_type(4))) _Float16 v4h;
typedef __attribute__((ext_vector_type(4))) float v4f;

// ---------------- prep1: degree count + weight transpose/convert ----------------

__global__ void prep1(const int* __restrict__ src, const int* __restrict__ dst,
                      int* __restrict__ ocnt, int* __restrict__ icnt, int E,
                      const float* __restrict__ W1, const float* __restrict__ W2,
                      const float* __restrict__ W3, half_t* __restrict__ Wt1,
                      half_t* __restrict__ Wt2, half_t* __restrict__ Wt3) {
    int t = blockIdx.x * blockDim.x + threadIdx.x;
    if (t < E) {
        atomicAdd(&ocnt[src[t]], 1);
        atomicAdd(&icnt[dst[t]], 1);
    } else {
        int u = t - E;
        if (u < 32768) {                      // W1: K=128, N=256
            int n = u >> 7, k = u & 127;
            Wt1[u] = (half_t)W1[(size_t)k * 256 + n];
        } else if (u < 65536) {               // W2: K=256, N=128
            int w = u - 32768;
            int n = w >> 8, k = w & 255;
            Wt2[w] = (half_t)W2[(size_t)k * 128 + n];
        } else if (u < 70656) {               // W3: K=128, N=40
            int w = u - 65536;
            int n = w >> 7, k = w & 127;
            Wt3[w] = (half_t)W3[(size_t)k * 40 + n];
        }
    }
}

// ---------------- scan (3-phase hierarchical) ----------------

__global__ __launch_bounds__(SCAN_TPB) void scan_reduce(const int* __restrict__ cnt,
                                                        int* __restrict__ blockSum, int n) {
    __shared__ int s[SCAN_TPB];
    int chunk = (n + SCAN_NB - 1) / SCAN_NB;
    int beg = blockIdx.x * chunk;
    int end = min(beg + chunk, n);
    int sum = 0;
    for (int i = beg + threadIdx.x; i < end; i += SCAN_TPB) sum += cnt[i];
    s[threadIdx.x] = sum;
    __syncthreads();
    for (int off = SCAN_TPB / 2; off > 0; off >>= 1) {
        if (threadIdx.x < off) s[threadIdx.x] += s[threadIdx.x + off];
        __syncthreads();
    }
    if (threadIdx.x == 0) blockSum[blockIdx.x] = s[0];
}

__global__ __launch_bounds__(SCAN_NB) void scan_offsets(int* __restrict__ blockSum,
                                                        int* __restrict__ rowptr_total) {
    __shared__ int s[SCAN_NB];
    int tid = threadIdx.x;
    int v = blockSum[tid];
    s[tid] = v;
    __syncthreads();
    for (int off = 1; off < SCAN_NB; off <<= 1) {
        int t = (tid >= off) ? s[tid - off] : 0;
        __syncthreads();
        s[tid] += t;
        __syncthreads();
    }
    blockSum[tid] = s[tid] - v;
    if (tid == SCAN_NB - 1) rowptr_total[0] = s[tid];
}

// Phase 3: in-chunk scan + block offset -> rowptr, cursor; also converts
// ocnt/icnt (int degree) -> inv-sqrt norms (float, in place).
__global__ __launch_bounds__(SCAN_TPB) void scan_final(int* __restrict__ cnt,
                                                       int* __restrict__ ocnt,
                                                       const int* __restrict__ blockSum,
                                                       int* __restrict__ rowptr,
                                                       int* __restrict__ cursor, int n) {
    __shared__ int s[SCAN_TPB];
    int chunk = (n + SCAN_NB - 1) / SCAN_NB;
    int beg = blockIdx.x * chunk;
    int end = min(beg + chunk, n);
    int carry = blockSum[blockIdx.x];
    for (int base = beg; base < end; base += SCAN_TPB) {
        int i = base + threadIdx.x;
        int v = (i < end) ? cnt[i] : 0;
        s[threadIdx.x] = v;
        __syncthreads();
        for (int off = 1; off < SCAN_TPB; off <<= 1) {
            int t = (threadIdx.x >= off) ? s[threadIdx.x - off] : 0;
            __syncthreads();
            s[threadIdx.x] += t;
            __syncthreads();
        }
        int excl = s[threadIdx.x] - v;
        if (i < end) {
            rowptr[i] = carry + excl;
            cursor[i] = carry + excl;
            int o = ocnt[i];
            ((float*)ocnt)[i] = rsqrtf((float)max(o, 1));
            ((float*)cnt)[i] = rsqrtf((float)max(v, 1));
        }
        int roundSum = s[SCAN_TPB - 1];
        __syncthreads();
        carry += roundSum;
    }
}

// ---------------- prep2: CSR fill + x convert (x * inv_out -> fp16) ----------------

__global__ void prep2(const int* __restrict__ src, const int* __restrict__ dst,
                      int* __restrict__ cursor, int* __restrict__ eidx, int E,
                      const float* __restrict__ x, const float* __restrict__ invOut,
                      half_t* __restrict__ xh) {
    int t = blockIdx.x * blockDim.x + threadIdx.x;
    if (t < E) {
        int pos = atomicAdd(&cursor[dst[t]], 1);
        eidx[pos] = src[t];
    } else {
        int u = t - E;
        if (u < N_NODES * 32) {
            int n = u >> 5;
            float4 v = ((const float4*)x)[u];
            float s = invOut[n];
            v4h h;
            h[0] = (half_t)(v.x * s);
            h[1] = (half_t)(v.y * s);
            h[2] = (half_t)(v.z * s);
            h[3] = (half_t)(v.w * s);
            *(v4h*)(xh + (size_t)u * 4) = h;
        }
    }
}

// ---------------- 4-edge-unrolled CSR row segment-sum into fp32 acc[8] ----------
// (8-wide unroll measured WORSE in R8: VGPR 72->88 dropped occupancy 23->17%.)

template <int F>
__device__ __forceinline__ void gather_row(const half_t* __restrict__ x,
                                           const int* __restrict__ eidx,
                                           int beg, int end, int c, float* acc) {
    int j = beg;
    int tail = beg + ((end - beg) & ~3);
    for (; j < tail; j += 4) {
        int s0 = eidx[j + 0], s1 = eidx[j + 1], s2 = eidx[j + 2], s3 = eidx[j + 3];
        v8h v0 = *(const v8h*)(x + (size_t)s0 * F + c * 8);
        v8h v1 = *(const v8h*)(x + (size_t)s1 * F + c * 8);
        v8h v2 = *(const v8h*)(x + (size_t)s2 * F + c * 8);
        v8h v3 = *(const v8h*)(x + (size_t)s3 * F + c * 8);
#pragma unroll
        for (int q = 0; q < 8; ++q)
            acc[q] += ((float)v0[q] + (float)v1[q]) + ((float)v2[q] + (float)v3[q]);
    }
    for (; j < end; ++j) {
        int s = eidx[j];
        v8h val = *(const v8h*)(x + (size_t)s * F + c * 8);
#pragma unroll
        for (int q = 0; q < 8; ++q) acc[q] += (float)val[q];
    }
}

// ---------------- fused gather + GEMM1 + GEMM2 (layers 1+2 transform) ----------
// A-tile (64 rows) = segsum(xh) via CSR gather; h1 = relu((A@W1)*invIn+b1)*invOut
// kept in LDS only; t2 = h1 @ W2 -> global fp16 (plain stores: L2 aggregates the
// 2B scattered epilogue writes — nontemporal measured 2x write amplification R8).

__global__ __launch_bounds__(256) void fused_l12(
    const half_t* __restrict__ xh, const int* __restrict__ rowptr,
    const int* __restrict__ eidx, const half_t* __restrict__ Wt1,
    const half_t* __restrict__ Wt2,
    const float* __restrict__ invIn, const float* __restrict__ invOut,
    const float* __restrict__ b1, half_t* __restrict__ t2) {
    constexpr int K1 = 128, K2 = 256, N2 = 128;
    constexpr int LDA = K1 + 8;
    constexpr int LDH = K2 + 8;
    __shared__ half_t As[64][LDA];
    __shared__ half_t h1S[64][LDH];
    __shared__ float iiS[64], ioS[64];
    const int tid = threadIdx.x;
    const int wave = tid >> 6, lane = tid & 63;
    const int quad = lane >> 4, l16 = lane & 15;
    const int m0 = blockIdx.x * 64;
    const int n0 = wave * 64;

    v8h b[4][4];
    float bv[4];
#pragma unroll
    for (int j = 0; j < 4; ++j) {
        int gn = n0 + j * 16 + l16;
        bv[j] = b1[gn];
#pragma unroll
        for (int kc = 0; kc < 4; ++kc)
            b[j][kc] = *(const v8h*)(Wt1 + (size_t)gn * K1 + kc * 32 + quad * 8);
    }
    if (tid < 64) {
        int gm = m0 + tid;
        bool ok = gm < N_NODES;
        iiS[tid] = ok ? invIn[gm] : 0.f;
        ioS[tid] = ok ? invOut[gm] : 0.f;
    }

    // gather phase: 64 rows x 16 chunks = 1024 tasks, 4 per thread
#pragma unroll
    for (int t = 0; t < 4; ++t) {
        int task = tid + t * 256;
        int r = task >> 4, c = task & 15;
        int gm = m0 + r;
        float acc[8] = {};
        if (gm < N_NODES)
            gather_row<K1>(xh, eidx, rowptr[gm], rowptr[gm + 1], c, acc);
        v8h o;
#pragma unroll
        for (int q = 0; q < 8; ++q) o[q] = (half_t)acc[q];
        *(v8h*)&As[r][c * 8] = o;
    }
    __syncthreads();

    // GEMM1 -> h1S (LDS)
    for (int mt = 0; mt < 4; ++mt) {
        v8h a[4];
#pragma unroll
        for (int kc = 0; kc < 4; ++kc)
            a[kc] = *(const v8h*)&As[mt * 16 + l16][kc * 32 + quad * 8];
        v4f acc[4] = {};
#pragma unroll
        for (int kc = 0; kc < 4; ++kc)
#pragma unroll
            for (int j = 0; j < 4; ++j)
                acc[j] = __builtin_amdgcn_mfma_f32_16x16x32_f16(a[kc], b[j][kc], acc[j], 0, 0, 0);
#pragma unroll
        for (int j = 0; j < 4; ++j) {
            int cn = n0 + j * 16 + l16;
#pragma unroll
            for (int r = 0; r < 4; ++r) {
                int lr = mt * 16 + quad * 4 + r;
                float z = (acc[j][r] * iiS[lr] + bv[j]) * ioS[lr];
                h1S[lr][cn] = (half_t)fmaxf(z, 0.f);
            }
        }
    }

    // B2 fragments
    v8h b2[2][8];
    const int n02 = wave * 32;
#pragma unroll
    for (int j = 0; j < 2; ++j) {
        int gn = n02 + j * 16 + l16;
#pragma unroll
        for (int kc = 0; kc < 8; ++kc)
            b2[j][kc] = *(const v8h*)(Wt2 + (size_t)gn * K2 + kc * 32 + quad * 8);
    }
    __syncthreads();

    // GEMM2: t2 = h1S @ W2
    for (int mt = 0; mt < 4; ++mt) {
        v8h a2[8];
#pragma unroll
        for (int kc = 0; kc < 8; ++kc)
            a2[kc] = *(const v8h*)&h1S[mt * 16 + l16][kc * 32 + quad * 8];
        v4f acc2[2] = {};
#pragma unroll
        for (int kc = 0; kc < 8; ++kc)
#pragma unroll
            for (int j = 0; j < 2; ++j)
                acc2[j] = __builtin_amdgcn_mfma_f32_16x16x32_f16(a2[kc], b2[j][kc], acc2[j], 0, 0, 0);
#pragma unroll
        for (int j = 0; j < 2; ++j) {
            int gn = n02 + j * 16 + l16;
#pragma unroll
            for (int r = 0; r < 4; ++r) {
                int gm = m0 + mt * 16 + quad * 4 + r;
                if (gm < N_NODES) t2[(size_t)gm * N2 + gn] = (half_t)acc2[j][r];
            }
        }
    }
}

// ---------------- fused gather(+relu epi) + GEMM, layer 3 ----------------

__global__ __launch_bounds__(256) void fused_l3(
    const half_t* __restrict__ t2, const int* __restrict__ rowptr,
    const int* __restrict__ eidx, const half_t* __restrict__ Wt3,
    const float* __restrict__ invIn, const float* __restrict__ invOut,
    const float* __restrict__ b2, half_t* __restrict__ t3) {
    constexpr int K = 128, N = 40, LDA = K + 8;
    __shared__ half_t As[64][LDA];
    const int tid = threadIdx.x;
    const int wave = tid >> 6, lane = tid & 63;
    const int quad = lane >> 4, l16 = lane & 15;
    const int m0 = blockIdx.x * 64;

    v8h b[3][4];
#pragma unroll
    for (int j = 0; j < 3; ++j) {
        int gn = j * 16 + l16;
#pragma unroll
        for (int kc = 0; kc < 4; ++kc)
            b[j][kc] = (gn < N) ? *(const v8h*)(Wt3 + (size_t)gn * K + kc * 32 + quad * 8)
                                : (v8h)(half_t)0;
    }

#pragma unroll
    for (int t = 0; t < 4; ++t) {
        int task = tid + t * 256;
        int r = task >> 4, c = task & 15;
        int gm = m0 + r;
        float acc[8] = {};
        float ii = 0.f, io = 0.f;
        if (gm < N_NODES) {
            ii = invIn[gm];
            io = invOut[gm];
            gather_row<K>(t2, eidx, rowptr[gm], rowptr[gm + 1], c, acc);
        }
        v8h o;
#pragma unroll
        for (int q = 0; q < 8; ++q)
            o[q] = (half_t)fmaxf((acc[q] * ii + b2[c * 8 + q]) * io, 0.f);
        *(v8h*)&As[r][c * 8] = o;
    }
    __syncthreads();

    {
        int mt = wave;
        v8h a[4];
#pragma unroll
        for (int kc = 0; kc < 4; ++kc)
            a[kc] = *(const v8h*)&As[mt * 16 + l16][kc * 32 + quad * 8];
        v4f acc[3] = {};
#pragma unroll
        for (int kc = 0; kc < 4; ++kc)
#pragma unroll
            for (int j = 0; j < 3; ++j)
                acc[j] = __builtin_amdgcn_mfma_f32_16x16x32_f16(a[kc], b[j][kc], acc[j], 0, 0, 0);
#pragma unroll
        for (int j = 0; j < 3; ++j) {
            int gn = j * 16 + l16;
            if (gn >= N) continue;
#pragma unroll
            for (int r = 0; r < 4; ++r) {
                int gm = m0 + mt * 16 + quad * 4 + r;
                if (gm < N_NODES) t3[(size_t)gm * N + gn] = (half_t)acc[j][r];
            }
        }
    }
}

// ---------------- final gather (fp16 rows, fp32 out) ----------------

__global__ void gather_final(const half_t* __restrict__ x,
                             const int* __restrict__ rowptr, const int* __restrict__ eidx,
                             float* __restrict__ out, const float* __restrict__ invIn,
                             const float* __restrict__ bias) {
    constexpr int F = 40, V = 5;
    int t = blockIdx.x * blockDim.x + threadIdx.x;
    int n = t / V;
    int v = t - n * V;
    if (n >= N_NODES) return;
    float acc[8] = {};
    gather_row<F>(x, eidx, rowptr[n], rowptr[n + 1], v, acc);
    float ii = invIn[n];
    float* o = out + (size_t)n * F + v * 8;
#pragma unroll
    for (int q = 0; q < 8; ++q) o[q] = acc[q] * ii + bias[v * 8 + q];
}

// ---------------- launch ----------------

extern "C" void kernel_launch(void* const* d_in, const int* in_sizes, int n_in,
                              void* d_out, int out_size, void* d_ws, size_t ws_size,
                              hipStream_t stream) {
    const float* x  = (const float*)d_in[0];
    const int* src  = (const int*)d_in[1];
    const int* dst  = (const int*)d_in[2];
    const float* W1 = (const float*)d_in[3];
    const float* b1 = (const float*)d_in[4];
    const float* W2 = (const float*)d_in[5];
    const float* b2 = (const float*)d_in[6];
    const float* W3 = (const float*)d_in[7];
    const float* b3 = (const float*)d_in[8];
    float* out = (float*)d_out;
    const int E = in_sizes[1];

    char* ws = (char*)d_ws;
    int* ocnt     = (int*)ws;                     // 100000 (becomes inv_out f32)
    int* icnt     = (int*)(ws + 400000);          // 100000 (becomes inv_in f32)
    int* rowptr   = (int*)(ws + 800000);          // 100001
    int* cursor   = (int*)(ws + 1200256);         // 100000
    int* eidx     = (int*)(ws + 1600256);         // 800000 (3.2 MB)
    int* blockSum = (int*)(ws + 4800256);         // 128
    half_t* Wt1   = (half_t*)(ws + 4800768);      // 256x128 fp16 (64 KB)
    half_t* Wt2   = (half_t*)(ws + 4866304);      // 128x256 fp16 (64 KB)
    half_t* Wt3   = (half_t*)(ws + 4931840);      // 40x128 fp16 (10 KB)
    half_t* buf0  = (half_t*)(ws + 5000192);      // 25.6 MB: xh, later t3
    half_t* buf1  = (half_t*)(ws + 30600192);     // 25.6 MB: t2
    const float* inv_out = (const float*)ocnt;
    const float* inv_in  = (const float*)icnt;

    // ---- CSR + norms + weight conversion ----
    hipMemsetAsync(ocnt, 0, 800000, stream);
    prep1<<<(E + 70656 + 255) / 256, 256, 0, stream>>>(src, dst, ocnt, icnt, E,
                                                       W1, W2, W3, Wt1, Wt2, Wt3);
    scan_reduce<<<SCAN_NB, SCAN_TPB, 0, stream>>>(icnt, blockSum, N_NODES);
    scan_offsets<<<1, SCAN_NB, 0, stream>>>(blockSum, rowptr + N_NODES);
    scan_final<<<SCAN_NB, SCAN_TPB, 0, stream>>>(icnt, ocnt, blockSum, rowptr, cursor, N_NODES);
    prep2<<<(E + N_NODES * 32 + 255) / 256, 256, 0, stream>>>(src, dst, cursor, eidx, E,
                                                              x, inv_out, buf0);

    const int NB = (N_NODES + 63) / 64;  // 1563

    // Layers 1+2: t2 = (relu((segsum(xh)@W1)*inv_in + b1)*inv_out) @ W2
    fused_l12<<<NB, 256, 0, stream>>>(buf0, rowptr, eidx, Wt1, Wt2,
                                      inv_in, inv_out, b1, buf1);
    // Layer 3: t3 = (relu((segsum(t2))*inv_in + b2)*inv_out) @ W3
    fused_l3<<<NB, 256, 0, stream>>>(buf1, rowptr, eidx, Wt3, inv_in, inv_out, b2, buf0);
    // Final gather: out = segsum(t3)*inv_in + b3
    gather_final<<<(N_NODES * 5 + 255) / 256, 256, 0, stream>>>(
        buf0, rowptr, eidx, out, inv_in, b3);
}

// Round 10
// 367.261 us; speedup vs baseline: 1.0971x; 1.0001x over previous
//
#include <hip/hip_runtime.h>

#define N_NODES 100000
#define SCAN_NB 128
#define SCAN_TPB 256

typedef _Float16 half_t;
typedef __attribute__((ext_vector_type(8))) _Float16 v8h;
typedef __attribute__((ext_vector_type(4))) _Float16 v4h;
typedef __attribute__((ext_vector_type(4))) float v4f;

// ---------------- prep1: degree count + weight transpose/convert ----------------

__global__ void prep1(const int* __restrict__ src, const int* __restrict__ dst,
                      int* __restrict__ ocnt, int* __restrict__ icnt, int E,
                      const float* __restrict__ W1, const float* __restrict__ W2,
                      const float* __restrict__ W3, half_t* __restrict__ Wt1,
                      half_t* __restrict__ Wt2, half_t* __restrict__ Wt3) {
    int t = blockIdx.x * blockDim.x + threadIdx.x;
    if (t < E) {
        atomicAdd(&ocnt[src[t]], 1);
        atomicAdd(&icnt[dst[t]], 1);
    } else {
        int u = t - E;
        if (u < 32768) {                      // W1: K=128, N=256
            int n = u >> 7, k = u & 127;
            Wt1[u] = (half_t)W1[(size_t)k * 256 + n];
        } else if (u < 65536) {               // W2: K=256, N=128
            int w = u - 32768;
            int n = w >> 8, k = w & 255;
            Wt2[w] = (half_t)W2[(size_t)k * 128 + n];
        } else if (u < 70656) {               // W3: K=128, N=40
            int w = u - 65536;
            int n = w >> 7, k = w & 127;
            Wt3[w] = (half_t)W3[(size_t)k * 40 + n];
        }
    }
}

// ---------------- scan (3-phase hierarchical) ----------------

__global__ __launch_bounds__(SCAN_TPB) void scan_reduce(const int* __restrict__ cnt,
                                                        int* __restrict__ blockSum, int n) {
    __shared__ int s[SCAN_TPB];
    int chunk = (n + SCAN_NB - 1) / SCAN_NB;
    int beg = blockIdx.x * chunk;
    int end = min(beg + chunk, n);
    int sum = 0;
    for (int i = beg + threadIdx.x; i < end; i += SCAN_TPB) sum += cnt[i];
    s[threadIdx.x] = sum;
    __syncthreads();
    for (int off = SCAN_TPB / 2; off > 0; off >>= 1) {
        if (threadIdx.x < off) s[threadIdx.x] += s[threadIdx.x + off];
        __syncthreads();
    }
    if (threadIdx.x == 0) blockSum[blockIdx.x] = s[0];
}

__global__ __launch_bounds__(SCAN_NB) void scan_offsets(int* __restrict__ blockSum,
                                                        int* __restrict__ rowptr_total) {
    __shared__ int s[SCAN_NB];
    int tid = threadIdx.x;
    int v = blockSum[tid];
    s[tid] = v;
    __syncthreads();
    for (int off = 1; off < SCAN_NB; off <<= 1) {
        int t = (tid >= off) ? s[tid - off] : 0;
        __syncthreads();
        s[tid] += t;
        __syncthreads();
    }
    blockSum[tid] = s[tid] - v;
    if (tid == SCAN_NB - 1) rowptr_total[0] = s[tid];
}

// Phase 3: in-chunk scan + block offset -> rowptr, cursor; also converts
// ocnt/icnt (int degree) -> inv-sqrt norms (float, in place).
__global__ __launch_bounds__(SCAN_TPB) void scan_final(int* __restrict__ cnt,
                                                       int* __restrict__ ocnt,
                                                       const int* __restrict__ blockSum,
                                                       int* __restrict__ rowptr,
                                                       int* __restrict__ cursor, int n) {
    __shared__ int s[SCAN_TPB];
    int chunk = (n + SCAN_NB - 1) / SCAN_NB;
    int beg = blockIdx.x * chunk;
    int end = min(beg + chunk, n);
    int carry = blockSum[blockIdx.x];
    for (int base = beg; base < end; base += SCAN_TPB) {
        int i = base + threadIdx.x;
        int v = (i < end) ? cnt[i] : 0;
        s[threadIdx.x] = v;
        __syncthreads();
        for (int off = 1; off < SCAN_TPB; off <<= 1) {
            int t = (threadIdx.x >= off) ? s[threadIdx.x - off] : 0;
            __syncthreads();
            s[threadIdx.x] += t;
            __syncthreads();
        }
        int excl = s[threadIdx.x] - v;
        if (i < end) {
            rowptr[i] = carry + excl;
            cursor[i] = carry + excl;
            int o = ocnt[i];
            ((float*)ocnt)[i] = rsqrtf((float)max(o, 1));
            ((float*)cnt)[i] = rsqrtf((float)max(v, 1));
        }
        int roundSum = s[SCAN_TPB - 1];
        __syncthreads();
        carry += roundSum;
    }
}

// ---------------- prep2: CSR fill + x convert (x * inv_out -> fp16) ----------------

__global__ void prep2(const int* __restrict__ src, const int* __restrict__ dst,
                      int* __restrict__ cursor, int* __restrict__ eidx, int E,
                      const float* __restrict__ x, const float* __restrict__ invOut,
                      half_t* __restrict__ xh) {
    int t = blockIdx.x * blockDim.x + threadIdx.x;
    if (t < E) {
        int pos = atomicAdd(&cursor[dst[t]], 1);
        eidx[pos] = src[t];
    } else {
        int u = t - E;
        if (u < N_NODES * 32) {
            int n = u >> 5;
            float4 v = ((const float4*)x)[u];
            float s = invOut[n];
            v4h h;
            h[0] = (half_t)(v.x * s);
            h[1] = (half_t)(v.y * s);
            h[2] = (half_t)(v.z * s);
            h[3] = (half_t)(v.w * s);
            *(v4h*)(xh + (size_t)u * 4) = h;
        }
    }
}

// ---------------- 4-edge-unrolled CSR row segment-sum into fp32 acc[8] ----------
// (8-wide unroll measured WORSE in R8: VGPR 72->88 dropped occupancy 23->17%.)

template <int F>
__device__ __forceinline__ void gather_row(const half_t* __restrict__ x,
                                           const int* __restrict__ eidx,
                                           int beg, int end, int c, float* acc) {
    int j = beg;
    int tail = beg + ((end - beg) & ~3);
    for (; j < tail; j += 4) {
        int s0 = eidx[j + 0], s1 = eidx[j + 1], s2 = eidx[j + 2], s3 = eidx[j + 3];
        v8h v0 = *(const v8h*)(x + (size_t)s0 * F + c * 8);
        v8h v1 = *(const v8h*)(x + (size_t)s1 * F + c * 8);
        v8h v2 = *(const v8h*)(x + (size_t)s2 * F + c * 8);
        v8h v3 = *(const v8h*)(x + (size_t)s3 * F + c * 8);
#pragma unroll
        for (int q = 0; q < 8; ++q)
            acc[q] += ((float)v0[q] + (float)v1[q]) + ((float)v2[q] + (float)v3[q]);
    }
    for (; j < end; ++j) {
        int s = eidx[j];
        v8h val = *(const v8h*)(x + (size_t)s * F + c * 8);
#pragma unroll
        for (int q = 0; q < 8; ++q) acc[q] += (float)val[q];
    }
}

// ---------------- fused gather + GEMM1 + GEMM2 (layers 1+2 transform) ----------
// 512 threads = 8 waves. A-tile (64 rows) = segsum(xh) via CSR gather (2 serial
// row-chunk tasks/thread, 2x waves vs R9 -> 2x outstanding scattered loads);
// h1 = relu((A@W1)*invIn+b1)*invOut kept in LDS; t2 = h1 @ W2 -> global fp16.
// Per wave: 32 GEMM1 cols (2 n-tiles), 16 GEMM2 cols (1 n-tile). Plain stores
// (nontemporal measured 2x write amplification in R8).

__global__ __launch_bounds__(512) void fused_l12(
    const half_t* __restrict__ xh, const int* __restrict__ rowptr,
    const int* __restrict__ eidx, const half_t* __restrict__ Wt1,
    const half_t* __restrict__ Wt2,
    const float* __restrict__ invIn, const float* __restrict__ invOut,
    const float* __restrict__ b1, half_t* __restrict__ t2) {
    constexpr int K1 = 128, K2 = 256, N2 = 128;
    constexpr int LDA = K1 + 8;
    constexpr int LDH = K2 + 8;
    __shared__ half_t As[64][LDA];
    __shared__ half_t h1S[64][LDH];
    __shared__ float iiS[64], ioS[64];
    const int tid = threadIdx.x;
    const int wave = tid >> 6, lane = tid & 63;
    const int quad = lane >> 4, l16 = lane & 15;
    const int m0 = blockIdx.x * 64;
    const int n0 = wave * 32;   // GEMM1 column span per wave (8 waves x 32 = 256)

    // B1 fragments into registers (overlap with gather)
    v8h b[2][4];
    float bv[2];
#pragma unroll
    for (int j = 0; j < 2; ++j) {
        int gn = n0 + j * 16 + l16;
        bv[j] = b1[gn];
#pragma unroll
        for (int kc = 0; kc < 4; ++kc)
            b[j][kc] = *(const v8h*)(Wt1 + (size_t)gn * K1 + kc * 32 + quad * 8);
    }
    if (tid < 64) {
        int gm = m0 + tid;
        bool ok = gm < N_NODES;
        iiS[tid] = ok ? invIn[gm] : 0.f;
        ioS[tid] = ok ? invOut[gm] : 0.f;
    }

    // gather phase: 64 rows x 16 chunks = 1024 tasks, 2 per thread
#pragma unroll
    for (int t = 0; t < 2; ++t) {
        int task = tid + t * 512;
        int r = task >> 4, c = task & 15;
        int gm = m0 + r;
        float acc[8] = {};
        if (gm < N_NODES)
            gather_row<K1>(xh, eidx, rowptr[gm], rowptr[gm + 1], c, acc);
        v8h o;
#pragma unroll
        for (int q = 0; q < 8; ++q) o[q] = (half_t)acc[q];
        *(v8h*)&As[r][c * 8] = o;
    }
    __syncthreads();

    // GEMM1 -> h1S (LDS): 4 m-tiles x 2 n-tiles per wave
    for (int mt = 0; mt < 4; ++mt) {
        v8h a[4];
#pragma unroll
        for (int kc = 0; kc < 4; ++kc)
            a[kc] = *(const v8h*)&As[mt * 16 + l16][kc * 32 + quad * 8];
        v4f acc[2] = {};
#pragma unroll
        for (int kc = 0; kc < 4; ++kc)
#pragma unroll
            for (int j = 0; j < 2; ++j)
                acc[j] = __builtin_amdgcn_mfma_f32_16x16x32_f16(a[kc], b[j][kc], acc[j], 0, 0, 0);
#pragma unroll
        for (int j = 0; j < 2; ++j) {
            int cn = n0 + j * 16 + l16;
#pragma unroll
            for (int r = 0; r < 4; ++r) {
                int lr = mt * 16 + quad * 4 + r;
                float z = (acc[j][r] * iiS[lr] + bv[j]) * ioS[lr];
                h1S[lr][cn] = (half_t)fmaxf(z, 0.f);
            }
        }
    }

    // B2 fragments: 1 n-tile per wave (8 x 16 = 128 cols)
    v8h b2[8];
    const int n02 = wave * 16;
    {
        int gn = n02 + l16;
#pragma unroll
        for (int kc = 0; kc < 8; ++kc)
            b2[kc] = *(const v8h*)(Wt2 + (size_t)gn * K2 + kc * 32 + quad * 8);
    }
    __syncthreads();

    // GEMM2: t2 = h1S @ W2
    for (int mt = 0; mt < 4; ++mt) {
        v8h a2[8];
#pragma unroll
        for (int kc = 0; kc < 8; ++kc)
            a2[kc] = *(const v8h*)&h1S[mt * 16 + l16][kc * 32 + quad * 8];
        v4f acc2 = {};
#pragma unroll
        for (int kc = 0; kc < 8; ++kc)
            acc2 = __builtin_amdgcn_mfma_f32_16x16x32_f16(a2[kc], b2[kc], acc2, 0, 0, 0);
        int gn = n02 + l16;
#pragma unroll
        for (int r = 0; r < 4; ++r) {
            int gm = m0 + mt * 16 + quad * 4 + r;
            if (gm < N_NODES) t2[(size_t)gm * N2 + gn] = (half_t)acc2[r];
        }
    }
}

// ---------------- fused gather(+relu epi) + GEMM, layer 3 ----------------
// 512 threads = 8 waves; gather 2 tasks/thread; waves 0-3 run the small MFMA.

__global__ __launch_bounds__(512) void fused_l3(
    const half_t* __restrict__ t2, const int* __restrict__ rowptr,
    const int* __restrict__ eidx, const half_t* __restrict__ Wt3,
    const float* __restrict__ invIn, const float* __restrict__ invOut,
    const float* __restrict__ b2, half_t* __restrict__ t3) {
    constexpr int K = 128, N = 40, LDA = K + 8;
    __shared__ half_t As[64][LDA];
    const int tid = threadIdx.x;
    const int wave = tid >> 6, lane = tid & 63;
    const int quad = lane >> 4, l16 = lane & 15;
    const int m0 = blockIdx.x * 64;

    v8h b[3][4];
#pragma unroll
    for (int j = 0; j < 3; ++j) {
        int gn = j * 16 + l16;
#pragma unroll
        for (int kc = 0; kc < 4; ++kc)
            b[j][kc] = (gn < N) ? *(const v8h*)(Wt3 + (size_t)gn * K + kc * 32 + quad * 8)
                                : (v8h)(half_t)0;
    }

    // gather phase with fused relu epilogue: 1024 tasks, 2 per thread
#pragma unroll
    for (int t = 0; t < 2; ++t) {
        int task = tid + t * 512;
        int r = task >> 4, c = task & 15;
        int gm = m0 + r;
        float acc[8] = {};
        float ii = 0.f, io = 0.f;
        if (gm < N_NODES) {
            ii = invIn[gm];
            io = invOut[gm];
            gather_row<K>(t2, eidx, rowptr[gm], rowptr[gm + 1], c, acc);
        }
        v8h o;
#pragma unroll
        for (int q = 0; q < 8; ++q)
            o[q] = (half_t)fmaxf((acc[q] * ii + b2[c * 8 + q]) * io, 0.f);
        *(v8h*)&As[r][c * 8] = o;
    }
    __syncthreads();

    if (wave < 4) {
        int mt = wave;
        v8h a[4];
#pragma unroll
        for (int kc = 0; kc < 4; ++kc)
            a[kc] = *(const v8h*)&As[mt * 16 + l16][kc * 32 + quad * 8];
        v4f acc[3] = {};
#pragma unroll
        for (int kc = 0; kc < 4; ++kc)
#pragma unroll
            for (int j = 0; j < 3; ++j)
                acc[j] = __builtin_amdgcn_mfma_f32_16x16x32_f16(a[kc], b[j][kc], acc[j], 0, 0, 0);
#pragma unroll
        for (int j = 0; j < 3; ++j) {
            int gn = j * 16 + l16;
            if (gn >= N) continue;
#pragma unroll
            for (int r = 0; r < 4; ++r) {
                int gm = m0 + mt * 16 + quad * 4 + r;
                if (gm < N_NODES) t3[(size_t)gm * N + gn] = (half_t)acc[j][r];
            }
        }
    }
}

// ---------------- final gather (fp16 rows, fp32 out) ----------------

__global__ void gather_final(const half_t* __restrict__ x,
                             const int* __restrict__ rowptr, const int* __restrict__ eidx,
                             float* __restrict__ out, const float* __restrict__ invIn,
                             const float* __restrict__ bias) {
    constexpr int F = 40, V = 5;
    int t = blockIdx.x * blockDim.x + threadIdx.x;
    int n = t / V;
    int v = t - n * V;
    if (n >= N_NODES) return;
    float acc[8] = {};
    gather_row<F>(x, eidx, rowptr[n], rowptr[n + 1], v, acc);
    float ii = invIn[n];
    float* o = out + (size_t)n * F + v * 8;
#pragma unroll
    for (int q = 0; q < 8; ++q) o[q] = acc[q] * ii + bias[v * 8 + q];
}

// ---------------- launch ----------------

extern "C" void kernel_launch(void* const* d_in, const int* in_sizes, int n_in,
                              void* d_out, int out_size, void* d_ws, size_t ws_size,
                              hipStream_t stream) {
    const float* x  = (const float*)d_in[0];
    const int* src  = (const int*)d_in[1];
    const int* dst  = (const int*)d_in[2];
    const float* W1 = (const float*)d_in[3];
    const float* b1 = (const float*)d_in[4];
    const float* W2 = (const float*)d_in[5];
    const float* b2 = (const float*)d_in[6];
    const float* W3 = (const float*)d_in[7];
    const float* b3 = (const float*)d_in[8];
    float* out = (float*)d_out;
    const int E = in_sizes[1];

    char* ws = (char*)d_ws;
    int* ocnt     = (int*)ws;                     // 100000 (becomes inv_out f32)
    int* icnt     = (int*)(ws + 400000);          // 100000 (becomes inv_in f32)
    int* rowptr   = (int*)(ws + 800000);          // 100001
    int* cursor   = (int*)(ws + 1200256);         // 100000
    int* eidx     = (int*)(ws + 1600256);         // 800000 (3.2 MB)
    int* blockSum = (int*)(ws + 4800256);         // 128
    half_t* Wt1   = (half_t*)(ws + 4800768);      // 256x128 fp16 (64 KB)
    half_t* Wt2   = (half_t*)(ws + 4866304);      // 128x256 fp16 (64 KB)
    half_t* Wt3   = (half_t*)(ws + 4931840);      // 40x128 fp16 (10 KB)
    half_t* buf0  = (half_t*)(ws + 5000192);      // 25.6 MB: xh, later t3
    half_t* buf1  = (half_t*)(ws + 30600192);     // 25.6 MB: t2
    const float* inv_out = (const float*)ocnt;
    const float* inv_in  = (const float*)icnt;

    // ---- CSR + norms + weight conversion ----
    hipMemsetAsync(ocnt, 0, 800000, stream);
    prep1<<<(E + 70656 + 255) / 256, 256, 0, stream>>>(src, dst, ocnt, icnt, E,
                                                       W1, W2, W3, Wt1, Wt2, Wt3);
    scan_reduce<<<SCAN_NB, SCAN_TPB, 0, stream>>>(icnt, blockSum, N_NODES);
    scan_offsets<<<1, SCAN_NB, 0, stream>>>(blockSum, rowptr + N_NODES);
    scan_final<<<SCAN_NB, SCAN_TPB, 0, stream>>>(icnt, ocnt, blockSum, rowptr, cursor, N_NODES);
    prep2<<<(E + N_NODES * 32 + 255) / 256, 256, 0, stream>>>(src, dst, cursor, eidx, E,
                                                              x, inv_out, buf0);

    const int NB = (N_NODES + 63) / 64;  // 1563

    // Layers 1+2: t2 = (relu((segsum(xh)@W1)*inv_in + b1)*inv_out) @ W2
    fused_l12<<<NB, 512, 0, stream>>>(buf0, rowptr, eidx, Wt1, Wt2,
                                      inv_in, inv_out, b1, buf1);
    // Layer 3: t3 = (relu((segsum(t2))*inv_in + b2)*inv_out) @ W3
    fused_l3<<<NB, 512, 0, stream>>>(buf1, rowptr, eidx, Wt3, inv_in, inv_out, b2, buf0);
    // Final gather: out = segsum(t3)*inv_in + b3
    gather_final<<<(N_NODES * 5 + 255) / 256, 256, 0, stream>>>(
        buf0, rowptr, eidx, out, inv_in, b3);
}

// Round 11
// 354.003 us; speedup vs baseline: 1.1382x; 1.0375x over previous
//
#include <hip/hip_runtime.h>

#define N_NODES 100000
#define SCAN_NB 128
#define SCAN_TPB 256

typedef _Float16 half_t;
typedef __attribute__((ext_vector_type(8))) _Float16 v8h;
typedef __attribute__((ext_vector_type(4))) _Float16 v4h;
typedef __attribute__((ext_vector_type(4))) float v4f;

// ---------------- prep1: degree count + weight transpose/convert ----------------

__global__ void prep1(const int* __restrict__ src, const int* __restrict__ dst,
                      int* __restrict__ ocnt, int* __restrict__ icnt, int E,
                      const float* __restrict__ W1, const float* __restrict__ W2,
                      const float* __restrict__ W3, half_t* __restrict__ Wt1,
                      half_t* __restrict__ Wt2, half_t* __restrict__ Wt3) {
    int t = blockIdx.x * blockDim.x + threadIdx.x;
    if (t < E) {
        atomicAdd(&ocnt[src[t]], 1);
        atomicAdd(&icnt[dst[t]], 1);
    } else {
        int u = t - E;
        if (u < 32768) {                      // W1: K=128, N=256
            int n = u >> 7, k = u & 127;
            Wt1[u] = (half_t)W1[(size_t)k * 256 + n];
        } else if (u < 65536) {               // W2: K=256, N=128
            int w = u - 32768;
            int n = w >> 8, k = w & 255;
            Wt2[w] = (half_t)W2[(size_t)k * 128 + n];
        } else if (u < 70656) {               // W3: K=128, N=40
            int w = u - 65536;
            int n = w >> 7, k = w & 127;
            Wt3[w] = (half_t)W3[(size_t)k * 40 + n];
        }
    }
}

// ---------------- scan (3-phase hierarchical) ----------------

__global__ __launch_bounds__(SCAN_TPB) void scan_reduce(const int* __restrict__ cnt,
                                                        int* __restrict__ blockSum, int n) {
    __shared__ int s[SCAN_TPB];
    int chunk = (n + SCAN_NB - 1) / SCAN_NB;
    int beg = blockIdx.x * chunk;
    int end = min(beg + chunk, n);
    int sum = 0;
    for (int i = beg + threadIdx.x; i < end; i += SCAN_TPB) sum += cnt[i];
    s[threadIdx.x] = sum;
    __syncthreads();
    for (int off = SCAN_TPB / 2; off > 0; off >>= 1) {
        if (threadIdx.x < off) s[threadIdx.x] += s[threadIdx.x + off];
        __syncthreads();
    }
    if (threadIdx.x == 0) blockSum[blockIdx.x] = s[0];
}

__global__ __launch_bounds__(SCAN_NB) void scan_offsets(int* __restrict__ blockSum,
                                                        int* __restrict__ rowptr_total) {
    __shared__ int s[SCAN_NB];
    int tid = threadIdx.x;
    int v = blockSum[tid];
    s[tid] = v;
    __syncthreads();
    for (int off = 1; off < SCAN_NB; off <<= 1) {
        int t = (tid >= off) ? s[tid - off] : 0;
        __syncthreads();
        s[tid] += t;
        __syncthreads();
    }
    blockSum[tid] = s[tid] - v;
    if (tid == SCAN_NB - 1) rowptr_total[0] = s[tid];
}

// Phase 3: in-chunk scan + block offset -> rowptr, cursor; also converts
// ocnt/icnt (int degree) -> inv-sqrt norms (float, in place).
__global__ __launch_bounds__(SCAN_TPB) void scan_final(int* __restrict__ cnt,
                                                       int* __restrict__ ocnt,
                                                       const int* __restrict__ blockSum,
                                                       int* __restrict__ rowptr,
                                                       int* __restrict__ cursor, int n) {
    __shared__ int s[SCAN_TPB];
    int chunk = (n + SCAN_NB - 1) / SCAN_NB;
    int beg = blockIdx.x * chunk;
    int end = min(beg + chunk, n);
    int carry = blockSum[blockIdx.x];
    for (int base = beg; base < end; base += SCAN_TPB) {
        int i = base + threadIdx.x;
        int v = (i < end) ? cnt[i] : 0;
        s[threadIdx.x] = v;
        __syncthreads();
        for (int off = 1; off < SCAN_TPB; off <<= 1) {
            int t = (threadIdx.x >= off) ? s[threadIdx.x - off] : 0;
            __syncthreads();
            s[threadIdx.x] += t;
            __syncthreads();
        }
        int excl = s[threadIdx.x] - v;
        if (i < end) {
            rowptr[i] = carry + excl;
            cursor[i] = carry + excl;
            int o = ocnt[i];
            ((float*)ocnt)[i] = rsqrtf((float)max(o, 1));
            ((float*)cnt)[i] = rsqrtf((float)max(v, 1));
        }
        int roundSum = s[SCAN_TPB - 1];
        __syncthreads();
        carry += roundSum;
    }
}

// ---------------- prep2: CSR fill + x convert (x * inv_out -> fp16) ----------------

__global__ void prep2(const int* __restrict__ src, const int* __restrict__ dst,
                      int* __restrict__ cursor, int* __restrict__ eidx, int E,
                      const float* __restrict__ x, const float* __restrict__ invOut,
                      half_t* __restrict__ xh) {
    int t = blockIdx.x * blockDim.x + threadIdx.x;
    if (t < E) {
        int pos = atomicAdd(&cursor[dst[t]], 1);
        eidx[pos] = src[t];
    } else {
        int u = t - E;
        if (u < N_NODES * 32) {
            int n = u >> 5;
            float4 v = ((const float4*)x)[u];
            float s = invOut[n];
            v4h h;
            h[0] = (half_t)(v.x * s);
            h[1] = (half_t)(v.y * s);
            h[2] = (half_t)(v.z * s);
            h[3] = (half_t)(v.w * s);
            *(v4h*)(xh + (size_t)u * 4) = h;
        }
    }
}

// ---------------- 4-edge-unrolled CSR row segment-sum into fp32 acc[8] ----------
// (8-wide unroll measured WORSE in R8: VGPR 72->88 dropped occupancy 23->17%.)

template <int F>
__device__ __forceinline__ void gather_row(const half_t* __restrict__ x,
                                           const int* __restrict__ eidx,
                                           int beg, int end, int c, float* acc) {
    int j = beg;
    int tail = beg + ((end - beg) & ~3);
    for (; j < tail; j += 4) {
        int s0 = eidx[j + 0], s1 = eidx[j + 1], s2 = eidx[j + 2], s3 = eidx[j + 3];
        v8h v0 = *(const v8h*)(x + (size_t)s0 * F + c * 8);
        v8h v1 = *(const v8h*)(x + (size_t)s1 * F + c * 8);
        v8h v2 = *(const v8h*)(x + (size_t)s2 * F + c * 8);
        v8h v3 = *(const v8h*)(x + (size_t)s3 * F + c * 8);
#pragma unroll
        for (int q = 0; q < 8; ++q)
            acc[q] += ((float)v0[q] + (float)v1[q]) + ((float)v2[q] + (float)v3[q]);
    }
    for (; j < end; ++j) {
        int s = eidx[j];
        v8h val = *(const v8h*)(x + (size_t)s * F + c * 8);
#pragma unroll
        for (int q = 0; q < 8; ++q) acc[q] += (float)val[q];
    }
}

// ---------------- fused gather + GEMM1 + GEMM2 (layers 1+2 transform) ----------
// 512 threads = 8 waves (R10: 86->73 us vs 256thr via 2x wave-level MLP).
// A-tile (64 rows) = segsum(xh) via CSR gather; h1 = relu((A@W1)*invIn+b1)*invOut
// kept in LDS; t2 = h1 @ W2 -> global fp16. Per wave: 32 GEMM1 cols, 16 GEMM2
// cols. Plain stores (nontemporal measured 2x write amplification in R8).

__global__ __launch_bounds__(512) void fused_l12(
    const half_t* __restrict__ xh, const int* __restrict__ rowptr,
    const int* __restrict__ eidx, const half_t* __restrict__ Wt1,
    const half_t* __restrict__ Wt2,
    const float* __restrict__ invIn, const float* __restrict__ invOut,
    const float* __restrict__ b1, half_t* __restrict__ t2) {
    constexpr int K1 = 128, K2 = 256, N2 = 128;
    constexpr int LDA = K1 + 8;
    constexpr int LDH = K2 + 8;
    __shared__ half_t As[64][LDA];
    __shared__ half_t h1S[64][LDH];
    __shared__ float iiS[64], ioS[64];
    const int tid = threadIdx.x;
    const int wave = tid >> 6, lane = tid & 63;
    const int quad = lane >> 4, l16 = lane & 15;
    const int m0 = blockIdx.x * 64;
    const int n0 = wave * 32;   // GEMM1 column span per wave (8 waves x 32 = 256)

    // B1 fragments into registers (overlap with gather)
    v8h b[2][4];
    float bv[2];
#pragma unroll
    for (int j = 0; j < 2; ++j) {
        int gn = n0 + j * 16 + l16;
        bv[j] = b1[gn];
#pragma unroll
        for (int kc = 0; kc < 4; ++kc)
            b[j][kc] = *(const v8h*)(Wt1 + (size_t)gn * K1 + kc * 32 + quad * 8);
    }
    if (tid < 64) {
        int gm = m0 + tid;
        bool ok = gm < N_NODES;
        iiS[tid] = ok ? invIn[gm] : 0.f;
        ioS[tid] = ok ? invOut[gm] : 0.f;
    }

    // gather phase: 64 rows x 16 chunks = 1024 tasks, 2 per thread
#pragma unroll
    for (int t = 0; t < 2; ++t) {
        int task = tid + t * 512;
        int r = task >> 4, c = task & 15;
        int gm = m0 + r;
        float acc[8] = {};
        if (gm < N_NODES)
            gather_row<K1>(xh, eidx, rowptr[gm], rowptr[gm + 1], c, acc);
        v8h o;
#pragma unroll
        for (int q = 0; q < 8; ++q) o[q] = (half_t)acc[q];
        *(v8h*)&As[r][c * 8] = o;
    }
    __syncthreads();

    // GEMM1 -> h1S (LDS): 4 m-tiles x 2 n-tiles per wave
    for (int mt = 0; mt < 4; ++mt) {
        v8h a[4];
#pragma unroll
        for (int kc = 0; kc < 4; ++kc)
            a[kc] = *(const v8h*)&As[mt * 16 + l16][kc * 32 + quad * 8];
        v4f acc[2] = {};
#pragma unroll
        for (int kc = 0; kc < 4; ++kc)
#pragma unroll
            for (int j = 0; j < 2; ++j)
                acc[j] = __builtin_amdgcn_mfma_f32_16x16x32_f16(a[kc], b[j][kc], acc[j], 0, 0, 0);
#pragma unroll
        for (int j = 0; j < 2; ++j) {
            int cn = n0 + j * 16 + l16;
#pragma unroll
            for (int r = 0; r < 4; ++r) {
                int lr = mt * 16 + quad * 4 + r;
                float z = (acc[j][r] * iiS[lr] + bv[j]) * ioS[lr];
                h1S[lr][cn] = (half_t)fmaxf(z, 0.f);
            }
        }
    }

    // B2 fragments: 1 n-tile per wave (8 x 16 = 128 cols)
    v8h b2[8];
    const int n02 = wave * 16;
    {
        int gn = n02 + l16;
#pragma unroll
        for (int kc = 0; kc < 8; ++kc)
            b2[kc] = *(const v8h*)(Wt2 + (size_t)gn * K2 + kc * 32 + quad * 8);
    }
    __syncthreads();

    // GEMM2: t2 = h1S @ W2
    for (int mt = 0; mt < 4; ++mt) {
        v8h a2[8];
#pragma unroll
        for (int kc = 0; kc < 8; ++kc)
            a2[kc] = *(const v8h*)&h1S[mt * 16 + l16][kc * 32 + quad * 8];
        v4f acc2 = {};
#pragma unroll
        for (int kc = 0; kc < 8; ++kc)
            acc2 = __builtin_amdgcn_mfma_f32_16x16x32_f16(a2[kc], b2[kc], acc2, 0, 0, 0);
        int gn = n02 + l16;
#pragma unroll
        for (int r = 0; r < 4; ++r) {
            int gm = m0 + mt * 16 + quad * 4 + r;
            if (gm < N_NODES) t2[(size_t)gm * N2 + gn] = (half_t)acc2[r];
        }
    }
}

// ---------------- fused gather(+relu epi) + GEMM, layer 3 ----------------
// 256 threads (R10 A/B: the 512-thr variant offset fused_l12's gain; R9 config
// restored — 4 gather tasks/thread, all 4 waves run the MFMA).

__global__ __launch_bounds__(256) void fused_l3(
    const half_t* __restrict__ t2, const int* __restrict__ rowptr,
    const int* __restrict__ eidx, const half_t* __restrict__ Wt3,
    const float* __restrict__ invIn, const float* __restrict__ invOut,
    const float* __restrict__ b2, half_t* __restrict__ t3) {
    constexpr int K = 128, N = 40, LDA = K + 8;
    __shared__ half_t As[64][LDA];
    const int tid = threadIdx.x;
    const int wave = tid >> 6, lane = tid & 63;
    const int quad = lane >> 4, l16 = lane & 15;
    const int m0 = blockIdx.x * 64;

    v8h b[3][4];
#pragma unroll
    for (int j = 0; j < 3; ++j) {
        int gn = j * 16 + l16;
#pragma unroll
        for (int kc = 0; kc < 4; ++kc)
            b[j][kc] = (gn < N) ? *(const v8h*)(Wt3 + (size_t)gn * K + kc * 32 + quad * 8)
                                : (v8h)(half_t)0;
    }

#pragma unroll
    for (int t = 0; t < 4; ++t) {
        int task = tid + t * 256;
        int r = task >> 4, c = task & 15;
        int gm = m0 + r;
        float acc[8] = {};
        float ii = 0.f, io = 0.f;
        if (gm < N_NODES) {
            ii = invIn[gm];
            io = invOut[gm];
            gather_row<K>(t2, eidx, rowptr[gm], rowptr[gm + 1], c, acc);
        }
        v8h o;
#pragma unroll
        for (int q = 0; q < 8; ++q)
            o[q] = (half_t)fmaxf((acc[q] * ii + b2[c * 8 + q]) * io, 0.f);
        *(v8h*)&As[r][c * 8] = o;
    }
    __syncthreads();

    {
        int mt = wave;
        v8h a[4];
#pragma unroll
        for (int kc = 0; kc < 4; ++kc)
            a[kc] = *(const v8h*)&As[mt * 16 + l16][kc * 32 + quad * 8];
        v4f acc[3] = {};
#pragma unroll
        for (int kc = 0; kc < 4; ++kc)
#pragma unroll
            for (int j = 0; j < 3; ++j)
                acc[j] = __builtin_amdgcn_mfma_f32_16x16x32_f16(a[kc], b[j][kc], acc[j], 0, 0, 0);
#pragma unroll
        for (int j = 0; j < 3; ++j) {
            int gn = j * 16 + l16;
            if (gn >= N) continue;
#pragma unroll
            for (int r = 0; r < 4; ++r) {
                int gm = m0 + mt * 16 + quad * 4 + r;
                if (gm < N_NODES) t3[(size_t)gm * N + gn] = (half_t)acc[j][r];
            }
        }
    }
}

// ---------------- final gather (fp16 rows, fp32 out) ----------------

__global__ void gather_final(const half_t* __restrict__ x,
                             const int* __restrict__ rowptr, const int* __restrict__ eidx,
                             float* __restrict__ out, const float* __restrict__ invIn,
                             const float* __restrict__ bias) {
    constexpr int F = 40, V = 5;
    int t = blockIdx.x * blockDim.x + threadIdx.x;
    int n = t / V;
    int v = t - n * V;
    if (n >= N_NODES) return;
    float acc[8] = {};
    gather_row<F>(x, eidx, rowptr[n], rowptr[n + 1], v, acc);
    float ii = invIn[n];
    float* o = out + (size_t)n * F + v * 8;
#pragma unroll
    for (int q = 0; q < 8; ++q) o[q] = acc[q] * ii + bias[v * 8 + q];
}

// ---------------- launch ----------------

extern "C" void kernel_launch(void* const* d_in, const int* in_sizes, int n_in,
                              void* d_out, int out_size, void* d_ws, size_t ws_size,
                              hipStream_t stream) {
    const float* x  = (const float*)d_in[0];
    const int* src  = (const int*)d_in[1];
    const int* dst  = (const int*)d_in[2];
    const float* W1 = (const float*)d_in[3];
    const float* b1 = (const float*)d_in[4];
    const float* W2 = (const float*)d_in[5];
    const float* b2 = (const float*)d_in[6];
    const float* W3 = (const float*)d_in[7];
    const float* b3 = (const float*)d_in[8];
    float* out = (float*)d_out;
    const int E = in_sizes[1];

    char* ws = (char*)d_ws;
    int* ocnt     = (int*)ws;                     // 100000 (becomes inv_out f32)
    int* icnt     = (int*)(ws + 400000);          // 100000 (becomes inv_in f32)
    int* rowptr   = (int*)(ws + 800000);          // 100001
    int* cursor   = (int*)(ws + 1200256);         // 100000
    int* eidx     = (int*)(ws + 1600256);         // 800000 (3.2 MB)
    int* blockSum = (int*)(ws + 4800256);         // 128
    half_t* Wt1   = (half_t*)(ws + 4800768);      // 256x128 fp16 (64 KB)
    half_t* Wt2   = (half_t*)(ws + 4866304);      // 128x256 fp16 (64 KB)
    half_t* Wt3   = (half_t*)(ws + 4931840);      // 40x128 fp16 (10 KB)
    half_t* buf0  = (half_t*)(ws + 5000192);      // 25.6 MB: xh, later t3
    half_t* buf1  = (half_t*)(ws + 30600192);     // 25.6 MB: t2
    const float* inv_out = (const float*)ocnt;
    const float* inv_in  = (const float*)icnt;

    // ---- CSR + norms + weight conversion ----
    hipMemsetAsync(ocnt, 0, 800000, stream);
    prep1<<<(E + 70656 + 255) / 256, 256, 0, stream>>>(src, dst, ocnt, icnt, E,
                                                       W1, W2, W3, Wt1, Wt2, Wt3);
    scan_reduce<<<SCAN_NB, SCAN_TPB, 0, stream>>>(icnt, blockSum, N_NODES);
    scan_offsets<<<1, SCAN_NB, 0, stream>>>(blockSum, rowptr + N_NODES);
    scan_final<<<SCAN_NB, SCAN_TPB, 0, stream>>>(icnt, ocnt, blockSum, rowptr, cursor, N_NODES);
    prep2<<<(E + N_NODES * 32 + 255) / 256, 256, 0, stream>>>(src, dst, cursor, eidx, E,
                                                              x, inv_out, buf0);

    const int NB = (N_NODES + 63) / 64;  // 1563

    // Layers 1+2: t2 = (relu((segsum(xh)@W1)*inv_in + b1)*inv_out) @ W2
    fused_l12<<<NB, 512, 0, stream>>>(buf0, rowptr, eidx, Wt1, Wt2,
                                      inv_in, inv_out, b1, buf1);
    // Layer 3: t3 = (relu((segsum(t2))*inv_in + b2)*inv_out) @ W3
    fused_l3<<<NB, 256, 0, stream>>>(buf1, rowptr, eidx, Wt3, inv_in, inv_out, b2, buf0);
    // Final gather: out = segsum(t3)*inv_in + b3
    gather_final<<<(N_NODES * 5 + 255) / 256, 256, 0, stream>>>(
        buf0, rowptr, eidx, out, inv_in, b3);
}